// Round 14
// baseline (126.693 us; speedup 1.0000x reference)
//
#include <hip/hip_runtime.h>

typedef __attribute__((ext_vector_type(2))) float f32x2;
typedef __attribute__((ext_vector_type(4))) float f32x4;
typedef __attribute__((ext_vector_type(8))) short s16x8;
typedef __attribute__((ext_vector_type(2))) unsigned int u32x2;
typedef __attribute__((ext_vector_type(4))) unsigned int u32x4;

#define BN 4
#define TN 4096
#define CN 120
#define HN 64

// RNE float->bf16 (finite inputs only)
__device__ __forceinline__ unsigned short f2bf(float f) {
  unsigned int u = __float_as_uint(f);
  unsigned int r = (u + 0x7fffu + ((u >> 16) & 1u)) >> 16;
  return (unsigned short)r;
}
__device__ __forceinline__ float fast_exp2(float x) {
#if __has_builtin(__builtin_amdgcn_exp2f)
  return __builtin_amdgcn_exp2f(x);
#else
  return exp2f(x);
#endif
}

// ---------------------------------------------------------------------------
// Workspace layouts (validated r10): K and V stored PRE-PERMUTED into MFMA
// fragment order so every in-loop global load in attn is base + lane*16.
//   Kf[b][kt]   : kt = key/16, 2KB tile. chunk0 byte L*16 = K[b][kt*16 +
//                 (L&15)][h=(L>>4)*8..+8); chunk1 (+1024B) same rows, h+32.
//   Qg[b*T+t][64] rows (bf16, pre-scaled by log2(e)/sqrt(120)).
//   Vf[b][kb32][ht]: 1KB: byte L*16 = V[b][h=ht*16+(L&15)][kb32*32 +
//                 (L>>4)*8..+8).
// ---------------------------------------------------------------------------

// ---------------------------------------------------------------------------
// Kernel 1: projections — UNCHANGED from rounds 10-13 (passing).
// ---------------------------------------------------------------------------
__global__ __launch_bounds__(256, 2) void proj_kernel(
    const float* __restrict__ x, const float* __restrict__ Wk,
    const float* __restrict__ Wq, const float* __restrict__ Wv,
    unsigned short* __restrict__ Kf, unsigned short* __restrict__ Qg,
    unsigned short* __restrict__ Vf) {
  __shared__ struct {
    float w[CN][HN];              // fp32 W for this block's mat     30720 B
    union {
      float xr[64][124];          // fp32 x rows (pitch 124)         31744 B
      unsigned short vt[64][72];  // transpose buffer (pitch 72)      9216 B
    } u;
  } sm;
  const int tid = threadIdx.x;
  const int mat = blockIdx.x >> 8;  // 0=K 1=Q 2=V
  const int rb = blockIdx.x & 255;
  const int row0 = rb * 64;
  const float* Ws = (mat == 0) ? Wk : (mat == 1) ? Wq : Wv;
  {  // stage W fp32, coalesced f32x4
    const f32x4* s = (const f32x4*)Ws;
    f32x4* d = (f32x4*)&sm.w[0][0];
    for (int i = tid; i < CN * HN / 4; i += 256) d[i] = s[i];
  }
  // stage x fp32 (row pitch 124 floats)
  for (int n = tid; n < 64 * 30; n += 256) {
    const int row = n / 30, c4 = n - row * 30;
    *(f32x4*)&sm.u.xr[row][c4 * 4] =
        *(const f32x4*)&x[(size_t)(row0 + row) * CN + c4 * 4];
  }
  __syncthreads();
  const int hg = tid & 15;  // h = hg*4 .. +3
  const int rg = tid >> 4;  // rows rg*4 .. +3
  f32x4 acc[4];
#pragma unroll
  for (int r = 0; r < 4; ++r) acc[r] = 0.f;
  for (int c = 0; c < CN; c += 4) {
    f32x4 xv[4];
#pragma unroll
    for (int r = 0; r < 4; ++r) xv[r] = *(const f32x4*)&sm.u.xr[rg * 4 + r][c];
#pragma unroll
    for (int cc = 0; cc < 4; ++cc) {
      const f32x4 wv = *(const f32x4*)&sm.w[c + cc][hg * 4];
#pragma unroll
      for (int r = 0; r < 4; ++r) acc[r] += wv * xv[r][cc];
    }
  }
  const int b = row0 >> 12, key0 = row0 & (TN - 1);
  if (mat == 1) {
    // Q: plain rows, pre-scaled by log2(e)/sqrt(120)
    const float sc = 0.13169944f;
#pragma unroll
    for (int r = 0; r < 4; ++r) {
      u32x2 wd;
      wd.x = (unsigned int)f2bf(acc[r][0] * sc) |
             ((unsigned int)f2bf(acc[r][1] * sc) << 16);
      wd.y = (unsigned int)f2bf(acc[r][2] * sc) |
             ((unsigned int)f2bf(acc[r][3] * sc) << 16);
      *(u32x2*)&Qg[(size_t)(row0 + rg * 4 + r) * HN + hg * 4] = wd;
    }
  } else if (mat == 0) {
    // K: store [key][h] rows in LDS, then emit frag-ordered Kf tiles
    __syncthreads();  // xr dead (union reuse)
#pragma unroll
    for (int r = 0; r < 4; ++r) {
      u32x2 wd;
      wd.x = (unsigned int)f2bf(acc[r][0]) |
             ((unsigned int)f2bf(acc[r][1]) << 16);
      wd.y = (unsigned int)f2bf(acc[r][2]) |
             ((unsigned int)f2bf(acc[r][3]) << 16);
      *(u32x2*)&sm.u.vt[rg * 4 + r][hg * 4] = wd;
    }
    __syncthreads();
#pragma unroll
    for (int i = 0; i < 2; ++i) {
      const int c = tid + i * 256;          // 512 chunks: 4 kt x 2 ch x 64 L
      const int ktl = c >> 7, ch = (c >> 6) & 1, L = c & 63;
      const u32x4 d =
          *(const u32x4*)&sm.u.vt[ktl * 16 + (L & 15)][(L >> 4) * 8 + ch * 32];
      *(u32x4*)((unsigned char*)Kf +
                (((size_t)b * 256 + (key0 >> 4) + ktl) * 128 + ch * 64 + L) *
                    16) = d;
    }
  } else {
    // V: store [h][key] in LDS, then emit frag-ordered Vf tiles
    __syncthreads();  // xr dead (union reuse)
#pragma unroll
    for (int r = 0; r < 4; ++r)
#pragma unroll
      for (int j = 0; j < 4; ++j)
        sm.u.vt[hg * 4 + j][rg * 4 + r] = f2bf(acc[r][j]);
    __syncthreads();
#pragma unroll
    for (int i = 0; i < 2; ++i) {
      const int c = tid + i * 256;          // 512 chunks: 2 kb32 x 4 ht x 64 L
      const int kbl = c >> 8, ht = (c >> 6) & 3, L = c & 63;
      const u32x4 d =
          *(const u32x4*)&sm.u.vt[ht * 16 + (L & 15)][kbl * 32 + (L >> 4) * 8];
      *(u32x4*)((unsigned char*)Vf +
                (((size_t)b * 128 + (key0 >> 5) + kbl) * 4 + ht) * 1024 +
                L * 16) = d;
    }
  }
}

// ---------------------------------------------------------------------------
// Kernel 2: attention — 64 QUERIES PER WAVE (qt=4). r13 accounting: L2 frag
// traffic 512MB (~15-22us) > VALU ~13us > MFMA 7us; q-width per wave is the
// only register-level sharing lever, so each K/V frag now serves 4 Q-tiles
// -> 256MB. Geometry: one 64q range per block, 8-way key split, grid 256 x
// 512 thr (1 block/CU, 25% occupancy -- fine: r8 showed we're request-
// throughput-bound, and all loads are single-segment).
// LDS fit: P built+consumed in 32-KEY HALVES (t0,t1 -> exp -> PV half0;
// t2,t3 -> exp -> PV half1): arena 8w x 4qt x 16q x 80B = 41KB <= 64KB.
// Per-(q,key) values AND accumulation order identical to r13 (verified
// 1.95e-3): lacc[qt] still sums in t-order, o[qt][ht] still kc-order ->
// bit-identical output. All private arrays literal-indexed (r12 lesson:
// runtime index -> lifetime scratch, 33MB HBM writes). VGPR ~150 under
// launch_bounds(512,2)'s 256 cap.
// ---------------------------------------------------------------------------
__global__ __launch_bounds__(512, 2) void attn_kernel(
    const unsigned short* __restrict__ Qg, const unsigned short* __restrict__ Kf,
    const unsigned short* __restrict__ Vf, float* __restrict__ out) {
  __shared__ union {
    unsigned short p[8][4][16][40];                      // 40960 B
    struct { float ob[8][64][17]; float lb[8][16]; } m;  // 35328 B
  } sm;
  const int bid = blockIdx.x;                      // [0,256)
  const int xslot = bid & 7;                       // XCD-aware swizzle
  const int b = xslot >> 1;                        // batch -> XCD pair
  const int qr = (bid >> 3) | ((xslot & 1) << 5);  // [0,64)
  const int qbase = qr * 64;
  const int tid = threadIdx.x;
  const int wave = tid >> 6, lane = tid & 63;
  const int l15 = lane & 15, quad = lane >> 4;

  // Q B-operand frags for 4 q-tiles: B[k=h][n=q]: q=l15, h=quad*8+j (+32)
  s16x8 qf[4][2];
#pragma unroll
  for (int qt = 0; qt < 4; ++qt) {
    const unsigned short* qrow =
        Qg + (size_t)(b * TN + qbase + qt * 16 + l15) * HN + quad * 8;
    qf[qt][0] = *(const s16x8*)qrow;
    qf[qt][1] = *(const s16x8*)(qrow + 32);
  }

  const unsigned char* Kfb = (const unsigned char*)Kf + (size_t)b * 524288;
  const unsigned char* Vfb = (const unsigned char*)Vf + (size_t)b * 524288;
  char* pw[4];
#pragma unroll
  for (int qt = 0; qt < 4; ++qt)
    pw[qt] = (char*)&sm.p[wave][qt][0][0] + l15 * 80;

  f32x4 o[4][4];
#pragma unroll
  for (int qt = 0; qt < 4; ++qt)
#pragma unroll
    for (int t = 0; t < 4; ++t) o[qt][t] = 0.f;
  float lacc[4] = {0.f, 0.f, 0.f, 0.f};

  const int kb0 = wave * 512;  // 8-way key split, 512 keys/wave
#pragma unroll 1
  for (int it = 0; it < 8; ++it) {
    const int kb = kb0 + it * 64;
    // two 32-key halves: S(2 tiles) -> exp/pack -> PV, keeps P at 32 keys
#pragma unroll
    for (int half = 0; half < 2; ++half) {
#pragma unroll
      for (int t2 = 0; t2 < 2; ++t2) {
        const unsigned char* ktp =
            Kfb + (size_t)((kb >> 4) + half * 2 + t2) * 2048 + lane * 16;
        const s16x8 a0 = *(const s16x8*)ktp;
        const s16x8 a1 = *(const s16x8*)(ktp + 1024);
        f32x4 s0 = 0.f, s1 = 0.f, s2 = 0.f, s3 = 0.f;
        s0 = __builtin_amdgcn_mfma_f32_16x16x32_bf16(a0, qf[0][0], s0, 0, 0, 0);
        s0 = __builtin_amdgcn_mfma_f32_16x16x32_bf16(a1, qf[0][1], s0, 0, 0, 0);
        s1 = __builtin_amdgcn_mfma_f32_16x16x32_bf16(a0, qf[1][0], s1, 0, 0, 0);
        s1 = __builtin_amdgcn_mfma_f32_16x16x32_bf16(a1, qf[1][1], s1, 0, 0, 0);
        s2 = __builtin_amdgcn_mfma_f32_16x16x32_bf16(a0, qf[2][0], s2, 0, 0, 0);
        s2 = __builtin_amdgcn_mfma_f32_16x16x32_bf16(a1, qf[2][1], s2, 0, 0, 0);
        s3 = __builtin_amdgcn_mfma_f32_16x16x32_bf16(a0, qf[3][0], s3, 0, 0, 0);
        s3 = __builtin_amdgcn_mfma_f32_16x16x32_bf16(a1, qf[3][1], s3, 0, 0, 0);
        // exp2, truncate to bf16, l from truncated values, store P^T.
        // C/D layout: q=l15(col), key-in-half = 16*t2 + quad*4 + reg.
#pragma unroll
        for (int qt = 0; qt < 4; ++qt) {
          const f32x4 s = (qt == 0) ? s0 : (qt == 1) ? s1 : (qt == 2) ? s2 : s3;
          unsigned int u0 = __float_as_uint(fast_exp2(fminf(s[0], 80.f)));
          unsigned int u1 = __float_as_uint(fast_exp2(fminf(s[1], 80.f)));
          unsigned int u2 = __float_as_uint(fast_exp2(fminf(s[2], 80.f)));
          unsigned int u3 = __float_as_uint(fast_exp2(fminf(s[3], 80.f)));
          u0 &= 0xffff0000u; u1 &= 0xffff0000u;
          u2 &= 0xffff0000u; u3 &= 0xffff0000u;
          lacc[qt] += (__uint_as_float(u0) + __uint_as_float(u1)) +
                      (__uint_as_float(u2) + __uint_as_float(u3));
          u32x2 w;
          w.x = (u0 >> 16) | u1;
          w.y = (u2 >> 16) | u3;
          *(u32x2*)(pw[qt] + t2 * 32 + quad * 8) = w;
        }
      }
      // ---- O^T += V * P^T for this 32-key half (V frag serves 4 qt) ----
      const s16x8 pb0 = *(const s16x8*)(pw[0] + quad * 16);
      const s16x8 pb1 = *(const s16x8*)(pw[1] + quad * 16);
      const s16x8 pb2 = *(const s16x8*)(pw[2] + quad * 16);
      const s16x8 pb3 = *(const s16x8*)(pw[3] + quad * 16);
#pragma unroll
      for (int ht = 0; ht < 4; ++ht) {
        const unsigned char* vtp =
            Vfb + (size_t)((kb >> 5) + half) * 4096 + ht * 1024 + lane * 16;
        const s16x8 va = *(const s16x8*)vtp;
        o[0][ht] = __builtin_amdgcn_mfma_f32_16x16x32_bf16(va, pb0, o[0][ht], 0, 0, 0);
        o[1][ht] = __builtin_amdgcn_mfma_f32_16x16x32_bf16(va, pb1, o[1][ht], 0, 0, 0);
        o[2][ht] = __builtin_amdgcn_mfma_f32_16x16x32_bf16(va, pb2, o[2][ht], 0, 0, 0);
        o[3][ht] = __builtin_amdgcn_mfma_f32_16x16x32_bf16(va, pb3, o[3][ht], 0, 0, 0);
      }
    }
  }
  // reduce l across quads (lane's column q=l15 fixed across quads)
#pragma unroll
  for (int qt = 0; qt < 4; ++qt) {
    lacc[qt] += __shfl_xor(lacc[qt], 16, 64);
    lacc[qt] += __shfl_xor(lacc[qt], 32, 64);
  }
  __syncthreads();  // all waves done with sm.p before union reuse
  // four-phase epilogue, FULLY UNROLLED (literal qt keeps o in VGPRs);
  // each phase = the verified r13 8-way merge
#pragma unroll
  for (int qt = 0; qt < 4; ++qt) {
    if (lane < 16) sm.m.lb[wave][l15] = lacc[qt];
#pragma unroll
    for (int ht = 0; ht < 4; ++ht)
#pragma unroll
      for (int r = 0; r < 4; ++r)
        sm.m.ob[wave][ht * 16 + quad * 4 + r][l15] = o[qt][ht][r];
    __syncthreads();
    const int h = tid & 63;
    const int wq = tid >> 6;  // 0..7
#pragma unroll
    for (int i = 0; i < 2; ++i) {
      const int qq = (i << 3) | wq;  // 0..15
      float ssum = 0.f, ll = 0.f;
#pragma unroll
      for (int w = 0; w < 8; ++w) {
        ssum += sm.m.ob[w][h][qq];
        ll += sm.m.lb[w][qq];
      }
      out[(size_t)(b * TN + qbase + qt * 16 + qq) * HN + h] = ssum / ll;
    }
    __syncthreads();  // phase qt's reads done before phase qt+1 overwrites
  }
}

extern "C" void kernel_launch(void* const* d_in, const int* in_sizes, int n_in,
                              void* d_out, int out_size, void* d_ws,
                              size_t ws_size, hipStream_t stream) {
  const float* x = (const float*)d_in[0];
  const float* Wk = (const float*)d_in[1];
  const float* Wq = (const float*)d_in[2];
  const float* Wv = (const float*)d_in[3];
  unsigned short* Kf = (unsigned short*)d_ws;             // [B][256] 2KB tiles
  unsigned short* Qg = Kf + (size_t)BN * TN * HN;         // [B*T][64] rows
  unsigned short* Vf = Qg + (size_t)BN * TN * HN;         // [B][128][4] 1KB
  float* out = (float*)d_out;
  proj_kernel<<<768, 256, 0, stream>>>(x, Wk, Wq, Wv, Kf, Qg, Vf);
  attn_kernel<<<256, 512, 0, stream>>>(Qg, Kf, Vf, out);
}

// Round 16
// 99.557 us; speedup vs baseline: 1.2726x; 1.2726x over previous
//
#include <hip/hip_runtime.h>

typedef __attribute__((ext_vector_type(2))) float f32x2;
typedef __attribute__((ext_vector_type(4))) float f32x4;
typedef __attribute__((ext_vector_type(8))) short s16x8;
typedef __attribute__((ext_vector_type(2))) unsigned int u32x2;
typedef __attribute__((ext_vector_type(4))) unsigned int u32x4;

#define BN 4
#define TN 4096
#define CN 120
#define HN 64

// RNE float->bf16 (finite inputs only)
__device__ __forceinline__ unsigned short f2bf(float f) {
  unsigned int u = __float_as_uint(f);
  unsigned int r = (u + 0x7fffu + ((u >> 16) & 1u)) >> 16;
  return (unsigned short)r;
}
__device__ __forceinline__ float bf2f(unsigned short h) {
  return __uint_as_float((unsigned int)h << 16);
}
__device__ __forceinline__ float fast_exp2(float x) {
#if __has_builtin(__builtin_amdgcn_exp2f)
  return __builtin_amdgcn_exp2f(x);
#else
  return exp2f(x);
#endif
}

// ---------------------------------------------------------------------------
// Workspace layouts (validated r10): K and V stored PRE-PERMUTED into MFMA
// fragment order so every in-loop global load in attn is base + lane*16.
//   Kf[b][kt]   : kt = key/16, 2KB tile. chunk0 byte L*16 = K[b][kt*16 +
//                 (L&15)][h=(L>>4)*8..+8); chunk1 (+1024B) same rows, h+32.
//   Qg[b*T+t][64] rows (bf16, pre-scaled by log2(e)/sqrt(120)).
//   Vf[b][kb32][ht]: 1KB: byte L*16 = V[b][h=ht*16+(L&15)][kb32*32 +
//                 (L>>4)*8..+8).
// ---------------------------------------------------------------------------

// ---------------------------------------------------------------------------
// Kernel 1: projections — MFMA engine (r15) with the r15 BUG FIXED: the Q
// epilogue wrote only ONE u32x4 per thread (16B) where each row-quarter is
// 32B -> half of every Q row was garbage (absmax 0.28). Now writes d0+d1
// exactly like the verified V/Kf emit paths. Everything else identical:
// x,W split hi/lo bf16 (3 MFMA terms, rel err ~2^-17 << bf16 output
// rounding), Q scale folded into W pre-split, K=120 zero-padded to 128,
// grid 768 (one mat/block), 4 waves x 16-h tile each.
// A-frag: m=l15, k=quad*8+j  |  B-frag: n=l15, k=quad*8+j  |
// C: col=l15(n), row=quad*4+reg(m)   [mappings attn-verified]
// ---------------------------------------------------------------------------
__global__ __launch_bounds__(256, 3) void proj_kernel(
    const float* __restrict__ x, const float* __restrict__ Wk,
    const float* __restrict__ Wq, const float* __restrict__ Wv,
    unsigned short* __restrict__ Kf, unsigned short* __restrict__ Qg,
    unsigned short* __restrict__ Vf) {
  __shared__ struct {
    unsigned short xh[64][136];  // bf16 hi, pitch 136 shorts       17408 B
    unsigned short xl[64][136];  // bf16 lo residual                17408 B
    unsigned short vt[64][72];   // transpose buffer (pitch 72)      9216 B
  } sm;
  const int tid = threadIdx.x;
  const int mat = blockIdx.x >> 8;  // 0=K 1=Q 2=V
  const int rb = blockIdx.x & 255;
  const int row0 = rb * 64;
  const int wave = tid >> 6, lane = tid & 63;
  const int l15 = lane & 15, quad = lane >> 4;
  const int b = row0 >> 12, key0 = row0 & (TN - 1);

  // ---- W B-frags (hi/lo) for this wave's h-tile ----
  const float* Ws = (mat == 0) ? Wk : (mat == 1) ? Wq : Wv;
  const float wsc = (mat == 1) ? 0.13169944f : 1.0f;  // log2(e)/sqrt(120)
  s16x8 wh[4], wl[4];
#pragma unroll
  for (int kc = 0; kc < 4; ++kc) {
#pragma unroll
    for (int j = 0; j < 8; ++j) {
      const int c = kc * 32 + quad * 8 + j;
      const float w = (c < CN) ? Ws[c * HN + wave * 16 + l15] * wsc : 0.f;
      const unsigned short h16 = f2bf(w);
      wh[kc][j] = (short)h16;
      wl[kc][j] = (short)f2bf(w - bf2f(h16));
    }
  }

  // ---- stage x: global f32x4 coalesced, split hi/lo during the copy ----
  for (int n = tid; n < 64 * 30; n += 256) {
    const int row = n / 30, c4 = n - row * 30;
    const f32x4 xv = *(const f32x4*)&x[(size_t)(row0 + row) * CN + c4 * 4];
    u32x2 hp, lp;
#pragma unroll
    for (int e = 0; e < 2; ++e) {
      const unsigned short h0 = f2bf(xv[2 * e]);
      const unsigned short h1 = f2bf(xv[2 * e + 1]);
      hp[e] = (unsigned int)h0 | ((unsigned int)h1 << 16);
      lp[e] = (unsigned int)f2bf(xv[2 * e] - bf2f(h0)) |
              ((unsigned int)f2bf(xv[2 * e + 1] - bf2f(h1)) << 16);
    }
    *(u32x2*)&sm.xh[row][c4 * 4] = hp;
    *(u32x2*)&sm.xl[row][c4 * 4] = lp;
  }
  if (tid < 64) {  // zero-pad c 120..127
    const u32x4 z = {0u, 0u, 0u, 0u};
    *(u32x4*)&sm.xh[tid][120] = z;
    *(u32x4*)&sm.xl[tid][120] = z;
  }
  __syncthreads();

  // ---- MFMA main: 4 m-tiles x 4 k-chunks x 3 split terms ----
  f32x4 acc[4];
#pragma unroll
  for (int mt = 0; mt < 4; ++mt) acc[mt] = 0.f;
#pragma unroll
  for (int mt = 0; mt < 4; ++mt) {
#pragma unroll
    for (int kc = 0; kc < 4; ++kc) {
      const s16x8 ah = *(const s16x8*)&sm.xh[mt * 16 + l15][kc * 32 + quad * 8];
      const s16x8 al = *(const s16x8*)&sm.xl[mt * 16 + l15][kc * 32 + quad * 8];
      acc[mt] = __builtin_amdgcn_mfma_f32_16x16x32_bf16(al, wh[kc], acc[mt], 0, 0, 0);
      acc[mt] = __builtin_amdgcn_mfma_f32_16x16x32_bf16(ah, wl[kc], acc[mt], 0, 0, 0);
      acc[mt] = __builtin_amdgcn_mfma_f32_16x16x32_bf16(ah, wh[kc], acc[mt], 0, 0, 0);
    }
  }

  // ---- epilogue: C-layout -> vt -> global ----
  if (mat < 2) {
    // rows in vt[row][h]
#pragma unroll
    for (int mt = 0; mt < 4; ++mt)
#pragma unroll
      for (int r = 0; r < 4; ++r)
        sm.vt[mt * 16 + quad * 4 + r][wave * 16 + l15] = f2bf(acc[mt][r]);
    __syncthreads();
    if (mat == 1) {
      // Qg rows — FIXED: each thread owns a 32B quarter-row -> TWO u32x4
      const int row = tid >> 2, seg = tid & 3;
      const u32x4 d0 = *(const u32x4*)&sm.vt[row][seg * 16];
      const u32x4 d1 = *(const u32x4*)&sm.vt[row][seg * 16 + 8];
      unsigned short* qp = &Qg[(size_t)(row0 + row) * HN + seg * 16];
      *(u32x4*)qp = d0;
      *(u32x4*)(qp + 8) = d1;
    } else {
      // Kf frag-ordered tiles (512 chunks, full coverage)
#pragma unroll
      for (int i = 0; i < 2; ++i) {
        const int c = tid + i * 256;  // 512 chunks: 4 kt x 2 ch x 64 L
        const int ktl = c >> 7, ch = (c >> 6) & 1, L = c & 63;
        const u32x4 d =
            *(const u32x4*)&sm.vt[ktl * 16 + (L & 15)][(L >> 4) * 8 + ch * 32];
        *(u32x4*)((unsigned char*)Kf +
                  (((size_t)b * 256 + (key0 >> 4) + ktl) * 128 + ch * 64 + L) *
                      16) = d;
      }
    }
  } else {
    // V transposed in vt[h][row]
#pragma unroll
    for (int mt = 0; mt < 4; ++mt)
#pragma unroll
      for (int r = 0; r < 4; ++r)
        sm.vt[wave * 16 + l15][mt * 16 + quad * 4 + r] = f2bf(acc[mt][r]);
    __syncthreads();
#pragma unroll
    for (int i = 0; i < 2; ++i) {
      const int c = tid + i * 256;  // 512 chunks: 2 kb32 x 4 ht x 64 L
      const int kbl = c >> 8, ht = (c >> 6) & 3, L = c & 63;
      const u32x4 d =
          *(const u32x4*)&sm.vt[ht * 16 + (L & 15)][kbl * 32 + (L >> 4) * 8];
      *(u32x4*)((unsigned char*)Vf +
                (((size_t)b * 128 + (key0 >> 5) + kbl) * 4 + ht) * 1024 +
                L * 16) = d;
    }
  }
}

// ---------------------------------------------------------------------------
// Kernel 2: attention — EXACT r13 kernel (verified pass, ~31us inferred).
// 32q/wave (2 Q-frags), grid 512 x 8 waves, 512 keys/wave, frag-ordered
// single-segment loads, spill-proof schedule, fully-unrolled epilogue.
// ---------------------------------------------------------------------------
__global__ __launch_bounds__(512, 4) void attn_kernel(
    const unsigned short* __restrict__ Qg, const unsigned short* __restrict__ Kf,
    const unsigned short* __restrict__ Vf, float* __restrict__ out) {
  __shared__ union {
    unsigned short p[8][2][16][72];                      // 36864 B
    struct { float ob[8][64][17]; float lb[8][16]; } m;  // 35328 B
  } sm;
  const int bid = blockIdx.x;                      // [0,512)
  const int xslot = bid & 7;                       // XCD-aware swizzle
  const int b = xslot >> 1;                        // batch -> XCD pair
  const int qt5 = (bid >> 3) | ((xslot & 1) << 6); // [0,128)
  const int qbase = qt5 * 32;
  const int tid = threadIdx.x;
  const int wave = tid >> 6, lane = tid & 63;
  const int l15 = lane & 15, quad = lane >> 4;

  // Q B-operand frags for both q-tiles: B[k=h][n=q]: q=l15, h=quad*8+j (+32)
  s16x8 qf[2][2];
#pragma unroll
  for (int qt = 0; qt < 2; ++qt) {
    const unsigned short* qrow =
        Qg + (size_t)(b * TN + qbase + qt * 16 + l15) * HN + quad * 8;
    qf[qt][0] = *(const s16x8*)qrow;
    qf[qt][1] = *(const s16x8*)(qrow + 32);
  }

  const unsigned char* Kfb = (const unsigned char*)Kf + (size_t)b * 524288;
  const unsigned char* Vfb = (const unsigned char*)Vf + (size_t)b * 524288;
  char* pw[2];
#pragma unroll
  for (int qt = 0; qt < 2; ++qt)
    pw[qt] = (char*)&sm.p[wave][qt][0][0] + l15 * 144;

  f32x4 o[2][4];
#pragma unroll
  for (int qt = 0; qt < 2; ++qt)
#pragma unroll
    for (int t = 0; t < 4; ++t) o[qt][t] = 0.f;
  float lacc[2] = {0.f, 0.f};

  const int kb0 = wave * 512;  // 8-way key split, 512 keys/wave
#pragma unroll 1
  for (int it = 0; it < 8; ++it) {
    const int kb = kb0 + it * 64;
    // ---- per 16-key tile t: S MFMAs then IMMEDIATE exp/pack (s dies) ----
#pragma unroll
    for (int t = 0; t < 4; ++t) {
      const unsigned char* ktp =
          Kfb + (size_t)((kb >> 4) + t) * 2048 + lane * 16;
      const s16x8 a0 = *(const s16x8*)ktp;
      const s16x8 a1 = *(const s16x8*)(ktp + 1024);
      f32x4 s0 = 0.f, s1 = 0.f;
      s0 = __builtin_amdgcn_mfma_f32_16x16x32_bf16(a0, qf[0][0], s0, 0, 0, 0);
      s0 = __builtin_amdgcn_mfma_f32_16x16x32_bf16(a1, qf[0][1], s0, 0, 0, 0);
      s1 = __builtin_amdgcn_mfma_f32_16x16x32_bf16(a0, qf[1][0], s1, 0, 0, 0);
      s1 = __builtin_amdgcn_mfma_f32_16x16x32_bf16(a1, qf[1][1], s1, 0, 0, 0);
      // exp2, truncate to bf16, l from truncated values, store P^T.
      // C/D layout: q=l15(col), key = 16t + quad*4 + reg.
#pragma unroll
      for (int qt = 0; qt < 2; ++qt) {
        const f32x4 s = qt ? s1 : s0;
        unsigned int u0 = __float_as_uint(fast_exp2(fminf(s[0], 80.f)));
        unsigned int u1 = __float_as_uint(fast_exp2(fminf(s[1], 80.f)));
        unsigned int u2 = __float_as_uint(fast_exp2(fminf(s[2], 80.f)));
        unsigned int u3 = __float_as_uint(fast_exp2(fminf(s[3], 80.f)));
        u0 &= 0xffff0000u; u1 &= 0xffff0000u;
        u2 &= 0xffff0000u; u3 &= 0xffff0000u;
        lacc[qt] += (__uint_as_float(u0) + __uint_as_float(u1)) +
                    (__uint_as_float(u2) + __uint_as_float(u3));
        u32x2 w;
        w.x = (u0 >> 16) | u1;
        w.y = (u2 >> 16) | u3;
        *(u32x2*)(pw[qt] + t * 32 + quad * 8) = w;  // keys 16t+quad*4..+3
      }
    }
    // ---- O^T += V * P^T (V frags reused 2x; same-wave LDS RAW) ----
#pragma unroll 1
    for (int kc = 0; kc < 2; ++kc) {
      const s16x8 pb0 = *(const s16x8*)(pw[0] + quad * 16 + kc * 64);
      const s16x8 pb1 = *(const s16x8*)(pw[1] + quad * 16 + kc * 64);
#pragma unroll
      for (int ht = 0; ht < 4; ++ht) {
        const unsigned char* vtp =
            Vfb + (size_t)((kb >> 5) + kc) * 4096 + ht * 1024 + lane * 16;
        const s16x8 va = *(const s16x8*)vtp;
        o[0][ht] = __builtin_amdgcn_mfma_f32_16x16x32_bf16(va, pb0, o[0][ht], 0, 0, 0);
        o[1][ht] = __builtin_amdgcn_mfma_f32_16x16x32_bf16(va, pb1, o[1][ht], 0, 0, 0);
      }
    }
  }
  // reduce l across quads (lane's column q=l15 fixed across quads)
#pragma unroll
  for (int qt = 0; qt < 2; ++qt) {
    lacc[qt] += __shfl_xor(lacc[qt], 16, 64);
    lacc[qt] += __shfl_xor(lacc[qt], 32, 64);
  }
  __syncthreads();  // all waves done with sm.p before union reuse
  // two-phase epilogue, FULLY UNROLLED (literal qt keeps o in VGPRs)
#pragma unroll
  for (int qt = 0; qt < 2; ++qt) {
    if (lane < 16) sm.m.lb[wave][l15] = lacc[qt];
#pragma unroll
    for (int ht = 0; ht < 4; ++ht)
#pragma unroll
      for (int r = 0; r < 4; ++r)
        sm.m.ob[wave][ht * 16 + quad * 4 + r][l15] = o[qt][ht][r];
    __syncthreads();
    const int h = tid & 63;
    const int wq = tid >> 6;  // 0..7
#pragma unroll
    for (int i = 0; i < 2; ++i) {
      const int qq = (i << 3) | wq;  // 0..15
      float ssum = 0.f, ll = 0.f;
#pragma unroll
      for (int w = 0; w < 8; ++w) {
        ssum += sm.m.ob[w][h][qq];
        ll += sm.m.lb[w][qq];
      }
      out[(size_t)(b * TN + qbase + qt * 16 + qq) * HN + h] = ssum / ll;
    }
    __syncthreads();  // phase qt's reads done before phase qt+1 overwrites
  }
}

extern "C" void kernel_launch(void* const* d_in, const int* in_sizes, int n_in,
                              void* d_out, int out_size, void* d_ws,
                              size_t ws_size, hipStream_t stream) {
  const float* x = (const float*)d_in[0];
  const float* Wk = (const float*)d_in[1];
  const float* Wq = (const float*)d_in[2];
  const float* Wv = (const float*)d_in[3];
  unsigned short* Kf = (unsigned short*)d_ws;             // [B][256] 2KB tiles
  unsigned short* Qg = Kf + (size_t)BN * TN * HN;         // [B*T][64] rows
  unsigned short* Vf = Qg + (size_t)BN * TN * HN;         // [B][128][4] 1KB
  float* out = (float*)d_out;
  proj_kernel<<<768, 256, 0, stream>>>(x, Wk, Wq, Wv, Kf, Qg, Vf);
  attn_kernel<<<BN * TN / 32, 512, 0, stream>>>(Qg, Kf, Vf, out);
}